// Round 7
// baseline (653.233 us; speedup 1.0000x reference)
//
#include <hip/hip_runtime.h>

#define N_NODES 20000
#define C 64
#define E_EDGES 320000
#define S_SPEC 64
#define R_DIM 8
#define HR 64
#define HEADS 2
#define TE 128
#define NT (E_EDGES/TE)          // 2500 blocks
#define HPAD 68                  // padded bf16 row stride (k-dim)
#define INV_AVG (1.0f/16.0f)

// out layout: node_out [0,40000) ; f_s [40000, 1320000) ; f_v [1320000, 5160000)
#define FS_OFF 40000
#define FV_OFF 1320000

typedef short bf16x4 __attribute__((ext_vector_type(4)));
typedef float f32x4  __attribute__((ext_vector_type(4)));

__device__ __forceinline__ unsigned short f2bf(float f){
  unsigned u = __float_as_uint(f);
  u += 0x7fffu + ((u >> 16) & 1u);
  return (unsigned short)(u >> 16);
}
__device__ __forceinline__ float bf2f(unsigned short b){
  return __uint_as_float(((unsigned)b) << 16);
}
__device__ __forceinline__ float phi_f(float x){
  float n = x * 0.5f;
  float s = (n > 0.0f) ? expf(-1.0f/n) : 0.0f;
  return 1.0f / (1.0f + n * s);
}

// ---------------- prep: Wr2T[n][k] = bf16(Wr2[k][n] / AVG)  (320x64) ------------------
__global__ __launch_bounds__(256) void wr2t_kernel(const float* __restrict__ Wr2,
                                                   unsigned short* __restrict__ wr2t){
  int idx = blockIdx.x*256 + threadIdx.x;      // n*64 + k
  int n = idx >> 6, k = idx & 63;
  wr2t[idx] = f2bf(Wr2[k*320 + n] * INV_AVG);
}

// ---------------- K1: up-projection, writes packed bf16 suv[n][c] = {s,v0,v1,v2} ------
__global__ __launch_bounds__(256) void node_up_kernel(
    const float* __restrict__ fs, const float* __restrict__ fv,
    const float* __restrict__ Wus, const float* __restrict__ Wuv,
    ushort4* __restrict__ suv){
  const int ni = threadIdx.x >> 6;
  const int d  = threadIdx.x & 63;
  const int n  = blockIdx.x*4 + ni;
  __shared__ float s_l[4][C];
  __shared__ float v_l[4][3][C];
  s_l[ni][d] = fs[n*C + d];
  #pragma unroll
  for (int x = 0; x < 3; ++x) v_l[ni][x][d] = fv[(n*C + d)*3 + x];
  __syncthreads();
  float as = 0.f, a0 = 0.f, a1 = 0.f, a2 = 0.f;
  #pragma unroll 4
  for (int c = 0; c < C; ++c){
    float wsv = Wus[c*C + d];
    float wvv = Wuv[c*C + d];
    as += s_l[ni][c] * wsv;
    a0 += v_l[ni][0][c] * wvv;
    a1 += v_l[ni][1][c] * wvv;
    a2 += v_l[ni][2][c] * wvv;
  }
  ushort4 o;
  o.x = f2bf(as); o.y = f2bf(a0); o.z = f2bf(a1); o.w = f2bf(a2);
  suv[(size_t)n*C + d] = o;
}

// ---------------- sort pass A: histogram of receivers ---------------------------------
__global__ __launch_bounds__(256) void hist_kernel(const int* __restrict__ rcv, int* __restrict__ count){
  int e = blockIdx.x*256 + threadIdx.x;
  atomicAdd(&count[rcv[e]], 1);
}

// ---------------- sort pass B: exclusive scan over 20000 counts (1 block) -------------
__global__ __launch_bounds__(1024) void scan_kernel(const int* __restrict__ count, int* __restrict__ cursor){
  __shared__ int sums[1024];
  const int t = threadIdx.x;
  const int base = t*20;
  int s = 0;
  #pragma unroll 4
  for (int i = 0; i < 20; ++i){ int idx = base+i; if (idx < N_NODES) s += count[idx]; }
  sums[t] = s;
  __syncthreads();
  for (int off = 1; off < 1024; off <<= 1){
    int v = (t >= off) ? sums[t-off] : 0;
    __syncthreads();
    sums[t] += v;
    __syncthreads();
  }
  int run = (t > 0) ? sums[t-1] : 0;
  for (int i = 0; i < 20; ++i){
    int idx = base+i;
    if (idx < N_NODES){ cursor[idx] = run; run += count[idx]; }
  }
}

// ---------------- sort pass C: scatter into sorted arrays, u pre-normalized ----------
__global__ __launch_bounds__(256) void scatter_kernel(
    const int* __restrict__ snd, const int* __restrict__ rcv,
    const float* __restrict__ ev, const float* __restrict__ re,
    int* __restrict__ cursor,
    int* __restrict__ snd_s, int* __restrict__ rcv_s,
    float4* __restrict__ u_s, float* __restrict__ re_s){
  int e = blockIdx.x*256 + threadIdx.x;
  int r = rcv[e];
  int pos = atomicAdd(&cursor[r], 1);
  snd_s[pos] = snd[e];
  rcv_s[pos] = r;
  float x = ev[e*3+0], y = ev[e*3+1], z = ev[e*3+2];
  float nr = sqrtf(x*x + y*y + z*z);
  float inv = 1.0f / fmaxf(nr, 1e-9f);
  float4 u4; u4.x = x*inv; u4.y = y*inv; u4.z = z*inv; u4.w = 0.f;
  u_s[pos] = u4;
  const float4* rp = (const float4*)&re[(size_t)e*R_DIM];
  float4 ra = rp[0], rb = rp[1];
  float4* op = (float4*)&re_s[(size_t)pos*R_DIM];
  op[0] = ra; op[1] = rb;
}

// ---------------- K2: MFMA radial GEMM, register-resident edges, 1 barrier ------------
__global__ __launch_bounds__(512, 6) void edge_kernel(
    const float4* __restrict__ u_s, const float* __restrict__ re_s,
    const int* __restrict__ snd_s, const int* __restrict__ rcv_s,
    const float* __restrict__ Wr1, const unsigned short* __restrict__ wr2t,
    const ushort4* __restrict__ suv,
    float* __restrict__ a_s, float* __restrict__ a_v)
{
  __shared__ __align__(16) float Wr1_l[R_DIM*HR];            // 2 KB
  __shared__ __align__(16) unsigned short Wr2T_l[320*HPAD];  // 43.5 KB bf16 [n][k] padded

  const int t = threadIdx.x;
  const int lane = t & 63;
  const int w = t >> 6;                 // wave 0..7 = 16-edge row-block
  // bijective XCD swizzle over 2500 blocks (2500 = 8*312 + 4)
  int b = blockIdx.x;
  int xcd = b & 7, idx = b >> 3;
  const int q = NT >> 3, r = NT & 7;
  int tile = (xcd < r ? xcd*(q+1) : r*(q+1) + (xcd-r)*q) + idx;
  const int e0 = tile * TE;

  // ---- stage Wr1, Wr2T (padded) ----
  Wr1_l[t] = Wr1[t];
  #pragma unroll
  for (int j = 0; j < 10; ++j){
    int i4 = t + 512*j;                 // ushort4 index, 5120 total
    ushort4 v4 = ((const ushort4*)wr2t)[i4];
    int el = i4*4; int n = el >> 6, k = el & 63;
    *(ushort4*)&Wr2T_l[n*HPAD + k] = v4;
  }

  // ---- per-lane edge state in registers (16-lane groups share addrs -> L1 bcast) ----
  const int arow = w*16 + (lane & 15);        // MFMA A row
  const int koff = 4*(lane >> 4);
  const int cl = lane & 15;
  const int ebase = w*16 + (lane >> 4)*4;     // this lane's 4 message edges
  float4 ra = ((const float4*)&re_s[(size_t)(e0 + arow)*R_DIM])[0];
  float4 rb = ((const float4*)&re_s[(size_t)(e0 + arow)*R_DIM])[1];
  float4 u4[4];
  int sn4[4], rc4[4];
  #pragma unroll
  for (int i = 0; i < 4; ++i){
    int e = e0 + ebase + i;
    u4[i] = u_s[e];
    sn4[i] = snd_s[e];
    rc4[i] = rcv_s[e];
  }
  __syncthreads();   // Wr2T ready (the only barrier)

  // ---- h in registers: lane computes exactly its A-fragment values ----
  bf16x4 ha[4];
  #pragma unroll
  for (int kt = 0; kt < 4; ++kt){
    short4 tmp;
    #pragma unroll
    for (int j = 0; j < 4; ++j){
      int k = kt*16 + koff + j;
      float acc = ra.x*Wr1_l[0*HR+k] + ra.y*Wr1_l[1*HR+k] + ra.z*Wr1_l[2*HR+k] + ra.w*Wr1_l[3*HR+k]
                + rb.x*Wr1_l[4*HR+k] + rb.y*Wr1_l[5*HR+k] + rb.z*Wr1_l[6*HR+k] + rb.w*Wr1_l[7*HR+k];
      float sil = acc / (1.0f + expf(-acc));
      ((unsigned short*)&tmp)[j] = f2bf(sil);
    }
    ha[kt] = *(bf16x4*)&tmp;
  }

  // ---- MFMA: W5[128][320], wave w owns rows w*16..+16, all 20 col-frags ----
  f32x4 acc[20];
  #pragma unroll
  for (int cf = 0; cf < 20; ++cf) acc[cf] = (f32x4){0.f,0.f,0.f,0.f};
  #pragma unroll
  for (int kt = 0; kt < 4; ++kt){
    bf16x4 af = ha[kt];
    #pragma unroll
    for (int cf = 0; cf < 20; ++cf){
      bf16x4 bf = *(const bf16x4*)&Wr2T_l[(cf*16 + (lane & 15))*HPAD + kt*16 + koff];
      acc[cf] = __builtin_amdgcn_mfma_f32_16x16x16bf16_1k(af, bf, acc[cf], 0, 0, 0);
    }
  }

  // ---- gather sender feats (bf16 packed), messages, run-length global atomics ----
  {
    ushort4 gv[4][4];
    #pragma unroll
    for (int i = 0; i < 4; ++i){
      const ushort4* sp_ = &suv[(size_t)sn4[i]*C];
      #pragma unroll
      for (int k2 = 0; k2 < 4; ++k2) gv[i][k2] = sp_[k2*16 + cl];
    }
    float ms[4], mv0[4], mv1[4], mv2[4];
    #pragma unroll
    for (int k2 = 0; k2 < 4; ++k2){ ms[k2]=0.f; mv0[k2]=0.f; mv1[k2]=0.f; mv2[k2]=0.f; }
    int cur = rc4[0];
    #pragma unroll
    for (int i = 0; i < 4; ++i){
      int rc = rc4[i];
      if (rc != cur){
        #pragma unroll
        for (int k2 = 0; k2 < 4; ++k2){
          int c = k2*16 + cl;
          unsafeAtomicAdd(&a_s[cur*C + c],       ms[k2]);
          unsafeAtomicAdd(&a_v[(cur*3+0)*C + c], mv0[k2]);
          unsafeAtomicAdd(&a_v[(cur*3+1)*C + c], mv1[k2]);
          unsafeAtomicAdd(&a_v[(cur*3+2)*C + c], mv2[k2]);
          ms[k2]=0.f; mv0[k2]=0.f; mv1[k2]=0.f; mv2[k2]=0.f;
        }
        cur = rc;
      }
      float u0 = u4[i].x, u1 = u4[i].y, u2 = u4[i].z;
      #pragma unroll
      for (int k2 = 0; k2 < 4; ++k2){
        float se  = bf2f(gv[i][k2].x);
        float ve0 = bf2f(gv[i][k2].y);
        float ve1 = bf2f(gv[i][k2].z);
        float ve2 = bf2f(gv[i][k2].w);
        float w0 = acc[0*4+k2][i];
        float w1 = acc[1*4+k2][i];
        float w2 = acc[2*4+k2][i];
        float w3 = acc[3*4+k2][i];
        float w4 = acc[4*4+k2][i];
        float dt  = ve0*u0 + ve1*u1 + ve2*u2;
        float cr0 = ve1*u2 - ve2*u1;
        float cr1 = ve2*u0 - ve0*u2;
        float cr2 = ve0*u1 - ve1*u0;
        ms[k2]  += w0*se + w3*dt;
        mv0[k2] += w1*ve0 + w2*u0 + w4*cr0;
        mv1[k2] += w1*ve1 + w2*u1 + w4*cr1;
        mv2[k2] += w1*ve2 + w2*u2 + w4*cr2;
      }
    }
    #pragma unroll
    for (int k2 = 0; k2 < 4; ++k2){
      int c = k2*16 + cl;
      unsafeAtomicAdd(&a_s[cur*C + c],       ms[k2]);
      unsafeAtomicAdd(&a_v[(cur*3+0)*C + c], mv0[k2]);
      unsafeAtomicAdd(&a_v[(cur*3+1)*C + c], mv1[k2]);
      unsafeAtomicAdd(&a_v[(cur*3+2)*C + c], mv2[k2]);
    }
  }
}

// ---------------- K3: down-matvec, product basis, soft-norm, residual, readout (4/blk)
__global__ __launch_bounds__(256) void node_post_kernel(
    const float* __restrict__ a_s, const float* __restrict__ a_v,
    const float* __restrict__ fs_in, const float* __restrict__ fv_in,
    const int* __restrict__ species,
    const float* __restrict__ W_rs, const float* __restrict__ W_rv,
    const float* __restrict__ W_ds, const float* __restrict__ W_dv,
    const float* __restrict__ w1s, const float* __restrict__ w1v,
    const float* __restrict__ w2ss, const float* __restrict__ w2vv, const float* __restrict__ w2sv,
    const float* __restrict__ W_ps, const float* __restrict__ W_pv,
    const float* __restrict__ w_read, float* __restrict__ out)
{
  const int ni = threadIdx.x >> 6;
  const int d  = threadIdx.x & 63;
  const int n  = blockIdx.x*4 + ni;
  const int sp = species[n];
  __shared__ float as_l[4][C];
  __shared__ float av_l[4][3][C];
  __shared__ float si_l[4][C];
  __shared__ float vi_l[4][3][C];
  as_l[ni][d] = a_s[n*C + d];
  #pragma unroll
  for (int x=0;x<3;x++) av_l[ni][x][d] = a_v[(n*3+x)*C + d];
  si_l[ni][d] = fs_in[n*C + d];
  #pragma unroll
  for (int x=0;x<3;x++) vi_l[ni][x][d] = fv_in[(n*C + d)*3 + x];
  __syncthreads();
  const float* Wrs_p = W_rs + sp*C*C;
  const float* Wrv_p = W_rv + sp*C*C;
  float bs=0, bv0=0, bv1=0, bv2=0, rs=0, rv0=0, rv1=0, rv2=0;
  for (int c=0;c<C;++c){
    float wds = W_ds[c*C+d], wdv = W_dv[c*C+d];
    float wrs = Wrs_p[c*C+d], wrv = Wrv_p[c*C+d];
    bs  += as_l[ni][c]*wds;
    bv0 += av_l[ni][0][c]*wdv; bv1 += av_l[ni][1][c]*wdv; bv2 += av_l[ni][2][c]*wdv;
    rs  += si_l[ni][c]*wrs;
    rv0 += vi_l[ni][0][c]*wrv; rv1 += vi_l[ni][1][c]*wrv; rv2 += vi_l[ni][2][c]*wrv;
  }
  float vv = bv0*bv0 + bv1*bv1 + bv2*bv2;
  float ps  = w1s[sp*C+d]*bs + w2ss[sp*C+d]*bs*bs + w2vv[sp*C+d]*vv;
  float c1v = w1v[sp*C+d], c2sv = w2sv[sp*C+d];
  float pv0 = c1v*bv0 + c2sv*bs*bv0;
  float pv1 = c1v*bv1 + c2sv*bs*bv1;
  float pv2 = c1v*bv2 + c2sv*bs*bv2;
  __syncthreads();
  as_l[ni][d] = ps; av_l[ni][0][d]=pv0; av_l[ni][1][d]=pv1; av_l[ni][2][d]=pv2;
  __syncthreads();
  float qs=0, qv0=0, qv1=0, qv2=0;
  for (int c=0;c<C;++c){
    float wps = W_ps[c*C+d], wpv = W_pv[c*C+d];
    qs  += as_l[ni][c]*wps;
    qv0 += av_l[ni][0][c]*wpv; qv1 += av_l[ni][1][c]*wpv; qv2 += av_l[ni][2][c]*wpv;
  }
  float fsv = qs * phi_f(fabsf(qs)) + rs;
  float nv = sqrtf(qv0*qv0 + qv1*qv1 + qv2*qv2);
  float ph = phi_f(nv);
  float fv0 = qv0*ph + rv0;
  float fv1 = qv1*ph + rv1;
  float fv2 = qv2*ph + rv2;
  out[FS_OFF + n*C + d] = fsv;
  float* fvo = &out[FV_OFF + (size_t)(n*C + d)*3];
  fvo[0]=fv0; fvo[1]=fv1; fvo[2]=fv2;
  #pragma unroll
  for (int h=0; h<HEADS; ++h){
    float r = fsv * w_read[h*C + d];
    #pragma unroll
    for (int off=32; off>0; off>>=1) r += __shfl_down(r, off);
    if (d == 0) out[n*HEADS + h] = r;
  }
}

extern "C" void kernel_launch(void* const* d_in, const int* in_sizes, int n_in,
                              void* d_out, int out_size, void* d_ws, size_t ws_size,
                              hipStream_t stream)
{
  const float* ev   = (const float*)d_in[0];
  const float* nfs  = (const float*)d_in[1];
  const float* nfv  = (const float*)d_in[2];
  const float* re   = (const float*)d_in[3];
  const int*   spec = (const int*)d_in[4];
  const int*   snd  = (const int*)d_in[5];
  const int*   rcv  = (const int*)d_in[6];
  const float* W_rs = (const float*)d_in[7];
  const float* W_rv = (const float*)d_in[8];
  const float* Wus  = (const float*)d_in[9];
  const float* Wuv  = (const float*)d_in[10];
  const float* Wr1  = (const float*)d_in[11];
  const float* Wr2  = (const float*)d_in[12];
  const float* Wds  = (const float*)d_in[13];
  const float* Wdv  = (const float*)d_in[14];
  const float* w1s  = (const float*)d_in[15];
  const float* w1v  = (const float*)d_in[16];
  const float* w2ss = (const float*)d_in[17];
  const float* w2vv = (const float*)d_in[18];
  const float* w2sv = (const float*)d_in[19];
  const float* Wps  = (const float*)d_in[20];
  const float* Wpv  = (const float*)d_in[21];
  const float* wrd  = (const float*)d_in[22];

  float* out = (float*)d_out;
  float* ws  = (float*)d_ws;
  // ws layout (f32 units)
  ushort4* suv  = (ushort4*)ws;            // 2,560,000 f32-equiv (10.24 MB)
  float*   a_s  = ws + 2560000;            // 1,280,000
  float*   a_v  = ws + 3840000;            // 3,840,000
  int*    count = (int*)(ws + 7680000);    // 20,000
  int*    cursr = (int*)(ws + 7700000);    // 20,000
  int*    snd_s = (int*)(ws + 7720000);    // 320,000
  int*    rcv_s = (int*)(ws + 8040000);    // 320,000
  float4* u_s   = (float4*)(ws + 8360000); // 1,280,000 f32 (16 B/edge)
  float*  re_s  = ws + 9640000;            // 2,560,000
  unsigned short* wr2t = (unsigned short*)(ws + 12200000);  // 20,480 bf16

  hipMemsetAsync(a_s, 0, (size_t)5120000*sizeof(float), stream);   // a_s + a_v
  hipMemsetAsync(count, 0, (size_t)N_NODES*sizeof(int), stream);

  wr2t_kernel<<<(320*64)/256, 256, 0, stream>>>(Wr2, wr2t);
  node_up_kernel<<<N_NODES/4, 256, 0, stream>>>(nfs, nfv, Wus, Wuv, suv);
  hist_kernel<<<E_EDGES/256, 256, 0, stream>>>(rcv, count);
  scan_kernel<<<1, 1024, 0, stream>>>(count, cursr);
  scatter_kernel<<<E_EDGES/256, 256, 0, stream>>>(snd, rcv, ev, re, cursr,
                                                  snd_s, rcv_s, u_s, re_s);
  edge_kernel<<<NT, 512, 0, stream>>>(u_s, re_s, snd_s, rcv_s, Wr1, wr2t,
                                      suv, a_s, a_v);
  node_post_kernel<<<N_NODES/4, 256, 0, stream>>>(a_s, a_v, nfs, nfv, spec,
      W_rs, W_rv, Wds, Wdv, w1s, w1v, w2ss, w2vv, w2sv, Wps, Wpv, wrd, out);
}

// Round 8
// 409.057 us; speedup vs baseline: 1.5969x; 1.5969x over previous
//
#include <hip/hip_runtime.h>

#define N_NODES 20000
#define C 64
#define E_EDGES 320000
#define S_SPEC 64
#define R_DIM 8
#define HR 64
#define HEADS 2
#define TE 64
#define NT (E_EDGES/TE)          // 5000 blocks = 8 x 625
#define HPAD 68                  // padded bf16 row stride (k-dim)
#define INV_AVG (1.0f/16.0f)

// out layout: node_out [0,40000) ; f_s [40000, 1320000) ; f_v [1320000, 5160000)
#define FS_OFF 40000
#define FV_OFF 1320000

typedef short bf16x4 __attribute__((ext_vector_type(4)));
typedef float f32x4  __attribute__((ext_vector_type(4)));

__device__ __forceinline__ unsigned short f2bf(float f){
  unsigned u = __float_as_uint(f);
  u += 0x7fffu + ((u >> 16) & 1u);
  return (unsigned short)(u >> 16);
}
__device__ __forceinline__ float bf2f(unsigned short b){
  return __uint_as_float(((unsigned)b) << 16);
}
__device__ __forceinline__ float phi_f(float x){
  float n = x * 0.5f;
  float s = (n > 0.0f) ? expf(-1.0f/n) : 0.0f;
  return 1.0f / (1.0f + n * s);
}

// ---------------- prep: Wr2T[n][k] = bf16(Wr2[k][n] / AVG)  (320x64) ------------------
__global__ __launch_bounds__(256) void wr2t_kernel(const float* __restrict__ Wr2,
                                                   unsigned short* __restrict__ wr2t){
  int idx = blockIdx.x*256 + threadIdx.x;      // n*64 + k
  int n = idx >> 6, k = idx & 63;
  wr2t[idx] = f2bf(Wr2[k*320 + n] * INV_AVG);
}

// ---------------- K1: up-projection, writes packed bf16 suv[n][c] = {s,v0,v1,v2} ------
__global__ __launch_bounds__(256) void node_up_kernel(
    const float* __restrict__ fs, const float* __restrict__ fv,
    const float* __restrict__ Wus, const float* __restrict__ Wuv,
    ushort4* __restrict__ suv){
  const int ni = threadIdx.x >> 6;
  const int d  = threadIdx.x & 63;
  const int n  = blockIdx.x*4 + ni;
  __shared__ float s_l[4][C];
  __shared__ float v_l[4][3][C];
  s_l[ni][d] = fs[n*C + d];
  #pragma unroll
  for (int x = 0; x < 3; ++x) v_l[ni][x][d] = fv[(n*C + d)*3 + x];
  __syncthreads();
  float as = 0.f, a0 = 0.f, a1 = 0.f, a2 = 0.f;
  #pragma unroll 4
  for (int c = 0; c < C; ++c){
    float wsv = Wus[c*C + d];
    float wvv = Wuv[c*C + d];
    as += s_l[ni][c] * wsv;
    a0 += v_l[ni][0][c] * wvv;
    a1 += v_l[ni][1][c] * wvv;
    a2 += v_l[ni][2][c] * wvv;
  }
  ushort4 o;
  o.x = f2bf(as); o.y = f2bf(a0); o.z = f2bf(a1); o.w = f2bf(a2);
  suv[(size_t)n*C + d] = o;
}

// ---------------- sort pass A: histogram of receivers ---------------------------------
__global__ __launch_bounds__(256) void hist_kernel(const int* __restrict__ rcv, int* __restrict__ count){
  int e = blockIdx.x*256 + threadIdx.x;
  atomicAdd(&count[rcv[e]], 1);
}

// ---------------- sort pass B: exclusive scan over 20000 counts (1 block) -------------
__global__ __launch_bounds__(1024) void scan_kernel(const int* __restrict__ count, int* __restrict__ cursor){
  __shared__ int sums[1024];
  const int t = threadIdx.x;
  const int base = t*20;
  int s = 0;
  #pragma unroll 4
  for (int i = 0; i < 20; ++i){ int idx = base+i; if (idx < N_NODES) s += count[idx]; }
  sums[t] = s;
  __syncthreads();
  for (int off = 1; off < 1024; off <<= 1){
    int v = (t >= off) ? sums[t-off] : 0;
    __syncthreads();
    sums[t] += v;
    __syncthreads();
  }
  int run = (t > 0) ? sums[t-1] : 0;
  for (int i = 0; i < 20; ++i){
    int idx = base+i;
    if (idx < N_NODES){ cursor[idx] = run; run += count[idx]; }
  }
}

// ---------------- sort pass C: scatter into sorted arrays, u pre-normalized ----------
__global__ __launch_bounds__(256) void scatter_kernel(
    const int* __restrict__ snd, const int* __restrict__ rcv,
    const float* __restrict__ ev, const float* __restrict__ re,
    int* __restrict__ cursor,
    int* __restrict__ snd_s, int* __restrict__ rcv_s,
    float4* __restrict__ u_s, float* __restrict__ re_s){
  int e = blockIdx.x*256 + threadIdx.x;
  int r = rcv[e];
  int pos = atomicAdd(&cursor[r], 1);
  snd_s[pos] = snd[e];
  rcv_s[pos] = r;
  float x = ev[e*3+0], y = ev[e*3+1], z = ev[e*3+2];
  float nr = sqrtf(x*x + y*y + z*z);
  float inv = 1.0f / fmaxf(nr, 1e-9f);
  float4 u4; u4.x = x*inv; u4.y = y*inv; u4.z = z*inv; u4.w = 0.f;
  u_s[pos] = u4;
  const float4* rp = (const float4*)&re[(size_t)e*R_DIM];
  float4 ra = rp[0], rb = rp[1];
  float4* op = (float4*)&re_s[(size_t)pos*R_DIM];
  op[0] = ra; op[1] = rb;
}

// ---------------- K2: MFMA radial GEMM, channel-split waves (acc=40 regs) -------------
// 8 waves = 4 edge-groups (16 edges each) x 2 column-halves (10 col-frags each).
__global__ __launch_bounds__(512, 6) void edge_kernel(
    const float4* __restrict__ u_s, const float* __restrict__ re_s,
    const int* __restrict__ snd_s, const int* __restrict__ rcv_s,
    const float* __restrict__ Wr1, const unsigned short* __restrict__ wr2t,
    const ushort4* __restrict__ suv,
    float* __restrict__ a_s, float* __restrict__ a_v)
{
  __shared__ __align__(16) float Wr1_l[R_DIM*HR];            // 2 KB
  __shared__ __align__(16) unsigned short Wr2T_l[320*HPAD];  // 43.5 KB bf16 [n][k] padded

  const int t = threadIdx.x;
  const int lane = t & 63;
  const int w = t >> 6;                 // wave 0..7
  const int g  = w >> 1;                // edge-group 0..3 (16 edges each)
  const int h2 = w & 1;                 // column half: k2 in {2*h2, 2*h2+1}
  // bijective XCD swizzle over 5000 blocks (5000 = 8*625)
  int b = blockIdx.x;
  int xcd = b & 7, idx = b >> 3;
  const int tile = xcd * (NT >> 3) + idx;
  const int e0 = tile * TE;

  // ---- stage Wr1, Wr2T (padded) ----
  Wr1_l[t] = Wr1[t];
  #pragma unroll
  for (int j = 0; j < 10; ++j){
    int i4 = t + 512*j;                 // ushort4 index, 5120 total
    ushort4 v4 = ((const ushort4*)wr2t)[i4];
    int el = i4*4; int n = el >> 6, k = el & 63;
    *(ushort4*)&Wr2T_l[n*HPAD + k] = v4;
  }

  // ---- per-lane edge state in registers (16-lane groups share addrs -> broadcast) ----
  const int arow = g*16 + (lane & 15);        // MFMA A row within tile
  const int koff = 4*(lane >> 4);
  const int cl = lane & 15;
  const int ebase = g*16 + (lane >> 4)*4;     // this lane's 4 message edges
  float4 ra = ((const float4*)&re_s[(size_t)(e0 + arow)*R_DIM])[0];
  float4 rb = ((const float4*)&re_s[(size_t)(e0 + arow)*R_DIM])[1];
  float u4x[4], u4y[4], u4z[4];
  int sn4[4], rc4[4];
  #pragma unroll
  for (int i = 0; i < 4; ++i){
    int e = e0 + ebase + i;
    float4 uu = u_s[e];
    u4x[i] = uu.x; u4y[i] = uu.y; u4z[i] = uu.z;
    sn4[i] = snd_s[e];
    rc4[i] = rcv_s[e];
  }
  __syncthreads();   // Wr2T ready (the only barrier)

  // ---- h in registers: lane computes exactly its A-fragment values ----
  bf16x4 ha[4];
  #pragma unroll
  for (int kt = 0; kt < 4; ++kt){
    short4 tmp;
    #pragma unroll
    for (int j = 0; j < 4; ++j){
      int k = kt*16 + koff + j;
      float acc = ra.x*Wr1_l[0*HR+k] + ra.y*Wr1_l[1*HR+k] + ra.z*Wr1_l[2*HR+k] + ra.w*Wr1_l[3*HR+k]
                + rb.x*Wr1_l[4*HR+k] + rb.y*Wr1_l[5*HR+k] + rb.z*Wr1_l[6*HR+k] + rb.w*Wr1_l[7*HR+k];
      float sil = acc / (1.0f + expf(-acc));
      ((unsigned short*)&tmp)[j] = f2bf(sil);
    }
    ha[kt] = *(bf16x4*)&tmp;
  }

  // ---- gather sender feats for this wave's 2 channel-groups (8 x 8B per lane) ----
  ushort4 gv[4][2];
  #pragma unroll
  for (int i = 0; i < 4; ++i){
    const ushort4* sp_ = &suv[(size_t)sn4[i]*C];
    #pragma unroll
    for (int kk = 0; kk < 2; ++kk) gv[i][kk] = sp_[(2*h2 + kk)*16 + cl];
  }

  // ---- MFMA: 10 col-frags = 5 paths x this wave's 2 channel-groups ----
  // frag lf = p*2 + kk  ->  col n = (p*4 + 2*h2 + kk)*16 + (lane&15)
  f32x4 acc[10];
  #pragma unroll
  for (int lf = 0; lf < 10; ++lf) acc[lf] = (f32x4){0.f,0.f,0.f,0.f};
  #pragma unroll
  for (int kt = 0; kt < 4; ++kt){
    bf16x4 af = ha[kt];
    #pragma unroll
    for (int lf = 0; lf < 10; ++lf){
      int p = lf >> 1, kk = lf & 1;
      int n = (p*4 + 2*h2 + kk)*16 + cl;
      bf16x4 bf = *(const bf16x4*)&Wr2T_l[n*HPAD + kt*16 + koff];
      acc[lf] = __builtin_amdgcn_mfma_f32_16x16x16bf16_1k(af, bf, acc[lf], 0, 0, 0);
    }
  }

  // ---- messages (2 channel-groups per lane) + run-length global atomics ----
  {
    float ms[2], mv0[2], mv1[2], mv2[2];
    #pragma unroll
    for (int kk = 0; kk < 2; ++kk){ ms[kk]=0.f; mv0[kk]=0.f; mv1[kk]=0.f; mv2[kk]=0.f; }
    int cur = rc4[0];
    #pragma unroll
    for (int i = 0; i < 4; ++i){
      int rc = rc4[i];
      if (rc != cur){
        #pragma unroll
        for (int kk = 0; kk < 2; ++kk){
          int c = (2*h2 + kk)*16 + cl;
          unsafeAtomicAdd(&a_s[cur*C + c],       ms[kk]);
          unsafeAtomicAdd(&a_v[(cur*3+0)*C + c], mv0[kk]);
          unsafeAtomicAdd(&a_v[(cur*3+1)*C + c], mv1[kk]);
          unsafeAtomicAdd(&a_v[(cur*3+2)*C + c], mv2[kk]);
          ms[kk]=0.f; mv0[kk]=0.f; mv1[kk]=0.f; mv2[kk]=0.f;
        }
        cur = rc;
      }
      float u0 = u4x[i], u1 = u4y[i], u2 = u4z[i];
      #pragma unroll
      for (int kk = 0; kk < 2; ++kk){
        float se  = bf2f(gv[i][kk].x);
        float ve0 = bf2f(gv[i][kk].y);
        float ve1 = bf2f(gv[i][kk].z);
        float ve2 = bf2f(gv[i][kk].w);
        float w0 = acc[0*2+kk][i];
        float w1 = acc[1*2+kk][i];
        float w2 = acc[2*2+kk][i];
        float w3 = acc[3*2+kk][i];
        float w4 = acc[4*2+kk][i];
        float dt  = ve0*u0 + ve1*u1 + ve2*u2;
        float cr0 = ve1*u2 - ve2*u1;
        float cr1 = ve2*u0 - ve0*u2;
        float cr2 = ve0*u1 - ve1*u0;
        ms[kk]  += w0*se + w3*dt;
        mv0[kk] += w1*ve0 + w2*u0 + w4*cr0;
        mv1[kk] += w1*ve1 + w2*u1 + w4*cr1;
        mv2[kk] += w1*ve2 + w2*u2 + w4*cr2;
      }
    }
    #pragma unroll
    for (int kk = 0; kk < 2; ++kk){
      int c = (2*h2 + kk)*16 + cl;
      unsafeAtomicAdd(&a_s[cur*C + c],       ms[kk]);
      unsafeAtomicAdd(&a_v[(cur*3+0)*C + c], mv0[kk]);
      unsafeAtomicAdd(&a_v[(cur*3+1)*C + c], mv1[kk]);
      unsafeAtomicAdd(&a_v[(cur*3+2)*C + c], mv2[kk]);
    }
  }
}

// ---------------- K3: down-matvec, product basis, soft-norm, residual, readout (4/blk)
__global__ __launch_bounds__(256) void node_post_kernel(
    const float* __restrict__ a_s, const float* __restrict__ a_v,
    const float* __restrict__ fs_in, const float* __restrict__ fv_in,
    const int* __restrict__ species,
    const float* __restrict__ W_rs, const float* __restrict__ W_rv,
    const float* __restrict__ W_ds, const float* __restrict__ W_dv,
    const float* __restrict__ w1s, const float* __restrict__ w1v,
    const float* __restrict__ w2ss, const float* __restrict__ w2vv, const float* __restrict__ w2sv,
    const float* __restrict__ W_ps, const float* __restrict__ W_pv,
    const float* __restrict__ w_read, float* __restrict__ out)
{
  const int ni = threadIdx.x >> 6;
  const int d  = threadIdx.x & 63;
  const int n  = blockIdx.x*4 + ni;
  const int sp = species[n];
  __shared__ float as_l[4][C];
  __shared__ float av_l[4][3][C];
  __shared__ float si_l[4][C];
  __shared__ float vi_l[4][3][C];
  as_l[ni][d] = a_s[n*C + d];
  #pragma unroll
  for (int x=0;x<3;x++) av_l[ni][x][d] = a_v[(n*3+x)*C + d];
  si_l[ni][d] = fs_in[n*C + d];
  #pragma unroll
  for (int x=0;x<3;x++) vi_l[ni][x][d] = fv_in[(n*C + d)*3 + x];
  __syncthreads();
  const float* Wrs_p = W_rs + sp*C*C;
  const float* Wrv_p = W_rv + sp*C*C;
  float bs=0, bv0=0, bv1=0, bv2=0, rs=0, rv0=0, rv1=0, rv2=0;
  for (int c=0;c<C;++c){
    float wds = W_ds[c*C+d], wdv = W_dv[c*C+d];
    float wrs = Wrs_p[c*C+d], wrv = Wrv_p[c*C+d];
    bs  += as_l[ni][c]*wds;
    bv0 += av_l[ni][0][c]*wdv; bv1 += av_l[ni][1][c]*wdv; bv2 += av_l[ni][2][c]*wdv;
    rs  += si_l[ni][c]*wrs;
    rv0 += vi_l[ni][0][c]*wrv; rv1 += vi_l[ni][1][c]*wrv; rv2 += vi_l[ni][2][c]*wrv;
  }
  float vv = bv0*bv0 + bv1*bv1 + bv2*bv2;
  float ps  = w1s[sp*C+d]*bs + w2ss[sp*C+d]*bs*bs + w2vv[sp*C+d]*vv;
  float c1v = w1v[sp*C+d], c2sv = w2sv[sp*C+d];
  float pv0 = c1v*bv0 + c2sv*bs*bv0;
  float pv1 = c1v*bv1 + c2sv*bs*bv1;
  float pv2 = c1v*bv2 + c2sv*bs*bv2;
  __syncthreads();
  as_l[ni][d] = ps; av_l[ni][0][d]=pv0; av_l[ni][1][d]=pv1; av_l[ni][2][d]=pv2;
  __syncthreads();
  float qs=0, qv0=0, qv1=0, qv2=0;
  for (int c=0;c<C;++c){
    float wps = W_ps[c*C+d], wpv = W_pv[c*C+d];
    qs  += as_l[ni][c]*wps;
    qv0 += av_l[ni][0][c]*wpv; qv1 += av_l[ni][1][c]*wpv; qv2 += av_l[ni][2][c]*wpv;
  }
  float fsv = qs * phi_f(fabsf(qs)) + rs;
  float nv = sqrtf(qv0*qv0 + qv1*qv1 + qv2*qv2);
  float ph = phi_f(nv);
  float fv0 = qv0*ph + rv0;
  float fv1 = qv1*ph + rv1;
  float fv2 = qv2*ph + rv2;
  out[FS_OFF + n*C + d] = fsv;
  float* fvo = &out[FV_OFF + (size_t)(n*C + d)*3];
  fvo[0]=fv0; fvo[1]=fv1; fvo[2]=fv2;
  #pragma unroll
  for (int h=0; h<HEADS; ++h){
    float r = fsv * w_read[h*C + d];
    #pragma unroll
    for (int off=32; off>0; off>>=1) r += __shfl_down(r, off);
    if (d == 0) out[n*HEADS + h] = r;
  }
}

extern "C" void kernel_launch(void* const* d_in, const int* in_sizes, int n_in,
                              void* d_out, int out_size, void* d_ws, size_t ws_size,
                              hipStream_t stream)
{
  const float* ev   = (const float*)d_in[0];
  const float* nfs  = (const float*)d_in[1];
  const float* nfv  = (const float*)d_in[2];
  const float* re   = (const float*)d_in[3];
  const int*   spec = (const int*)d_in[4];
  const int*   snd  = (const int*)d_in[5];
  const int*   rcv  = (const int*)d_in[6];
  const float* W_rs = (const float*)d_in[7];
  const float* W_rv = (const float*)d_in[8];
  const float* Wus  = (const float*)d_in[9];
  const float* Wuv  = (const float*)d_in[10];
  const float* Wr1  = (const float*)d_in[11];
  const float* Wr2  = (const float*)d_in[12];
  const float* Wds  = (const float*)d_in[13];
  const float* Wdv  = (const float*)d_in[14];
  const float* w1s  = (const float*)d_in[15];
  const float* w1v  = (const float*)d_in[16];
  const float* w2ss = (const float*)d_in[17];
  const float* w2vv = (const float*)d_in[18];
  const float* w2sv = (const float*)d_in[19];
  const float* Wps  = (const float*)d_in[20];
  const float* Wpv  = (const float*)d_in[21];
  const float* wrd  = (const float*)d_in[22];

  float* out = (float*)d_out;
  float* ws  = (float*)d_ws;
  // ws layout (f32 units)
  ushort4* suv  = (ushort4*)ws;            // 2,560,000 f32-equiv (10.24 MB)
  float*   a_s  = ws + 2560000;            // 1,280,000
  float*   a_v  = ws + 3840000;            // 3,840,000
  int*    count = (int*)(ws + 7680000);    // 20,000
  int*    cursr = (int*)(ws + 7700000);    // 20,000
  int*    snd_s = (int*)(ws + 7720000);    // 320,000
  int*    rcv_s = (int*)(ws + 8040000);    // 320,000
  float4* u_s   = (float4*)(ws + 8360000); // 1,280,000 f32 (16 B/edge)
  float*  re_s  = ws + 9640000;            // 2,560,000
  unsigned short* wr2t = (unsigned short*)(ws + 12200000);  // 20,480 bf16

  hipMemsetAsync(a_s, 0, (size_t)5120000*sizeof(float), stream);   // a_s + a_v
  hipMemsetAsync(count, 0, (size_t)N_NODES*sizeof(int), stream);

  wr2t_kernel<<<(320*64)/256, 256, 0, stream>>>(Wr2, wr2t);
  node_up_kernel<<<N_NODES/4, 256, 0, stream>>>(nfs, nfv, Wus, Wuv, suv);
  hist_kernel<<<E_EDGES/256, 256, 0, stream>>>(rcv, count);
  scan_kernel<<<1, 1024, 0, stream>>>(count, cursr);
  scatter_kernel<<<E_EDGES/256, 256, 0, stream>>>(snd, rcv, ev, re, cursr,
                                                  snd_s, rcv_s, u_s, re_s);
  edge_kernel<<<NT, 512, 0, stream>>>(u_s, re_s, snd_s, rcv_s, Wr1, wr2t,
                                      suv, a_s, a_v);
  node_post_kernel<<<N_NODES/4, 256, 0, stream>>>(a_s, a_v, nfs, nfv, spec,
      W_rs, W_rv, Wds, Wdv, w1s, w1v, w2ss, w2vv, w2sv, Wps, Wpv, wrd, out);
}